// Round 5
// baseline (17725.316 us; speedup 1.0000x reference)
//
#include <hip/hip_runtime.h>
#include <cstdint>
#include <cstddef>

// ---------------------------------------------------------------------------
// QLSTM: LSTM scan (recurrence) + batch-axis attention quirk, all-f16 internal.
// Pipeline: prep -> cvt_x -> GEMM xproj (gate-permuted epi) -> scan ->
//           GEMM qkv -> fused per-(s,h) attention -> GEMM out_proj (+Hseq add)
// R5 scan: 64 WGs x 512 thr, thread t = (unit u=t>>1, pair p=t&1) owns gate
//   cols u*4+2p, u*4+2p+1. Weights per thread = 256 u32 (f16x2): 192 in VGPR
//   (k=0..191; request sized BELOW the allocator's proven 232-reg keep-point,
//   R4 post-mortem), 64 in LDS as a manual spill (128 KB, b128 reads).
//   One barrier/step (double-buffered hx); (f,i)<->(g,o) exchange via
//   __shfl_xor(1) — no LDS gates round-trip.
// ws map (bytes):
//   [0, 134217728)          Xp f16 [1024][64][256u][4g] (reused: qkv@0, ctx@96M)
//   [134217728, +33554432)  Xh f16 [65536][256]
//   [167772160, +33554432)  Hseq_h f16 [65536][256]
//   [201326592, +524288)    W_scan f16 [r=128 k-pairs][1024 cols][2]
//   [201850880, +524288)    Wxt frag-major f16 (N=1024,K=256)
//   [202375168, +393216)    in_proj frag-major f16 (N=768,K=256)
//   [202768384, +131072)    out_proj frag-major f16 (N=256,K=256)
//   [202899456, +4096)      bias4 f32 [1024] (gate-major g*256+j)
// ---------------------------------------------------------------------------

typedef _Float16 f16;
typedef __attribute__((ext_vector_type(2))) _Float16 half2v;
typedef __attribute__((ext_vector_type(4))) _Float16 half4v;
typedef __attribute__((ext_vector_type(8))) _Float16 half8v;
typedef __attribute__((ext_vector_type(4))) float   float4v;

static __device__ __forceinline__ half2v u2h(unsigned u) {
  union { unsigned u; half2v h; } x; x.u = u; return x.h;
}
static __device__ __forceinline__ float sigm(float x) {
  return 1.0f / (1.0f + __expf(-x));
}
static __device__ __forceinline__ float tanh_fast(float x) {
  x = fminf(15.0f, fmaxf(-15.0f, x));
  float e = __expf(2.0f * x);
  return (e - 1.0f) / (e + 1.0f);
}
static __device__ __forceinline__ const float* selW(int g, const float* a, const float* b,
                                                    const float* c, const float* d) {
  return g == 0 ? a : (g == 1 ? b : (g == 2 ? c : d));
}

// ---------------------------------------------------------------------------
// prep: build f16 weight layouts.
//  seg0: W_scan [r=128][c=1024][e=2]: c = u*4+g, k = 2r+e,
//        value = W_g[(256+k)*256 + u]
//  seg1: Wxt frag-major (N=1024)  seg2: in_proj (N=768)  seg3: out_proj (N=256)
//  seg4: bias4[g*256+j] = b_g[j]
// frag-major B layout: flat = ((ntile*8 + kstep)*64 + lane)*8 + j ;
//   n = ntile*16 + (lane&15); k = kstep*32 + ((lane>>4)&3)*8 + j
// ---------------------------------------------------------------------------
__global__ void prep_k(const float* __restrict__ Wf, const float* __restrict__ Wi,
                       const float* __restrict__ Wg_, const float* __restrict__ Wo,
                       const float* __restrict__ bf, const float* __restrict__ bi,
                       const float* __restrict__ bg_, const float* __restrict__ bo,
                       const float* __restrict__ inpw, const float* __restrict__ outpw,
                       f16* __restrict__ wscan, f16* __restrict__ wxt,
                       f16* __restrict__ inpj, f16* __restrict__ outpj,
                       float* __restrict__ bias4)
{
  const int total = 262144 + 262144 + 196608 + 65536 + 1024;
  for (int e = blockIdx.x * blockDim.x + threadIdx.x; e < total; e += gridDim.x * blockDim.x) {
    int x = e;
    if (x < 262144) {                 // W_scan [r][c][2]
      int r = x >> 11, c = (x >> 1) & 1023, ee = x & 1;
      int k = 2 * r + ee, u = c >> 2, g = c & 3;
      const float* W = selW(g, Wf, Wi, Wg_, Wo);
      wscan[x] = (f16)W[(256 + k) * 256 + u];
      continue;
    }
    x -= 262144;
    if (x < 262144) {                 // Wxt frag-major (N=1024)
      int j = x & 7, lane = (x >> 3) & 63, kstep = (x >> 9) & 7, ntile = x >> 12;
      int n = ntile * 16 + (lane & 15);
      int k = kstep * 32 + ((lane >> 4) & 3) * 8 + j;
      int g = n >> 8, jj = n & 255;
      const float* W = selW(g, Wf, Wi, Wg_, Wo);
      wxt[x] = (f16)W[k * 256 + jj];
      continue;
    }
    x -= 262144;
    if (x < 196608) {                 // in_proj frag-major (N=768)
      int j = x & 7, lane = (x >> 3) & 63, kstep = (x >> 9) & 7, ntile = x >> 12;
      int n = ntile * 16 + (lane & 15);
      int k = kstep * 32 + ((lane >> 4) & 3) * 8 + j;
      inpj[x] = (f16)inpw[k * 768 + n];
      continue;
    }
    x -= 196608;
    if (x < 65536) {                  // out_proj frag-major (N=256)
      int j = x & 7, lane = (x >> 3) & 63, kstep = (x >> 9) & 7, ntile = x >> 12;
      int n = ntile * 16 + (lane & 15);
      int k = kstep * 32 + ((lane >> 4) & 3) * 8 + j;
      outpj[x] = (f16)outpw[k * 256 + n];
      continue;
    }
    x -= 65536;
    {                                 // bias4
      int g = x >> 8, j = x & 255;
      const float* bp = selW(g, bf, bi, bg_, bo);
      bias4[x] = bp[j];
    }
  }
}

// ---------------------------------------------------------------------------
__global__ void cvt_x_k(const float4v* __restrict__ X, half4v* __restrict__ Xh)
{
  int i = blockIdx.x * 256 + threadIdx.x;   // grid sized exactly: 16777216/4
  float4v v = X[i];
  half4v h;
  h.x = (f16)v.x; h.y = (f16)v.y; h.z = (f16)v.z; h.w = (f16)v.w;
  Xh[i] = h;
}

// ---------------------------------------------------------------------------
// Generic MFMA GEMM: C[65536][NTOT] = A[65536][256](f16) @ Bfrag + bias[n].
// EPI=0: store f16 plain.  EPI=1: store f16 gate-permuted (col = (n&255)*4 +
// (n>>8); requires NTOT=1024).  EPI=2: f32 accumulate-add (out_proj).
// ---------------------------------------------------------------------------
template<int NTOT, int EPI>
__global__ __launch_bounds__(256, 2) void gemm_k(const f16* __restrict__ A,
    const f16* __restrict__ Bf, const float* __restrict__ bias,
    f16* __restrict__ Oh, float* __restrict__ Of)
{
  __shared__ f16 Al[8192];            // [8 mtiles][2 ksteps][64 lanes][8]
  const int tid = threadIdx.x;
  const int lane = tid & 63;
  const int wm = (tid >> 7) & 1;
  const int wn = (tid >> 6) & 1;
  const int m0 = blockIdx.y * 128, n0 = blockIdx.x * 128;

  float4v acc[4][4];
  #pragma unroll
  for (int i = 0; i < 4; ++i)
    #pragma unroll
    for (int j = 0; j < 4; ++j) { acc[i][j].x = 0.f; acc[i][j].y = 0.f; acc[i][j].z = 0.f; acc[i][j].w = 0.f; }

  #pragma unroll 1
  for (int kc = 0; kc < 4; ++kc) {
    __syncthreads();
    #pragma unroll
    for (int p = 0; p < 4; ++p) {
      int m = p * 32 + (tid >> 3);
      int kk = (tid & 7) * 8;
      half8v v = *(const half8v*)(A + (size_t)(m0 + m) * 256 + kc * 64 + kk);
      int lt = ((kk >> 3) & 3) * 16 + (m & 15);
      *(half8v*)(Al + (((m >> 4) * 2 + (kk >> 5)) * 64 + lt) * 8) = v;
    }
    __syncthreads();
    half8v bfr[4][2], afr[4][2];
    #pragma unroll
    for (int i = 0; i < 4; ++i) {
      int NT = (n0 >> 4) + wn * 4 + i;
      #pragma unroll
      for (int ks = 0; ks < 2; ++ks)
        bfr[i][ks] = *(const half8v*)(Bf + (size_t)((NT * 8 + kc * 2 + ks) * 64 + lane) * 8);
    }
    #pragma unroll
    for (int i = 0; i < 4; ++i) {
      int MT = wm * 4 + i;
      #pragma unroll
      for (int ks = 0; ks < 2; ++ks)
        afr[i][ks] = *(const half8v*)(Al + ((MT * 2 + ks) * 64 + lane) * 8);
    }
    #pragma unroll
    for (int ks = 0; ks < 2; ++ks)
      #pragma unroll
      for (int i = 0; i < 4; ++i)
        #pragma unroll
        for (int jn = 0; jn < 4; ++jn)
          acc[i][jn] = __builtin_amdgcn_mfma_f32_16x16x32_f16(afr[i][ks], bfr[jn][ks], acc[i][jn], 0, 0, 0);
  }

  const int r0 = (lane >> 4) * 4, cn = lane & 15;
  #pragma unroll
  for (int i = 0; i < 4; ++i) {
    #pragma unroll
    for (int jn = 0; jn < 4; ++jn) {
      int n = n0 + wn * 64 + jn * 16 + cn;
      float bv = bias[n];
      int col = (EPI == 1) ? ((n & 255) * 4 + (n >> 8)) : n;
      int mb = m0 + wm * 64 + i * 16 + r0;
      #pragma unroll
      for (int r = 0; r < 4; ++r) {
        float v = acc[i][jn][r] + bv;
        size_t off = (size_t)(mb + r) * NTOT + col;
        if constexpr (EPI == 2) Of[off] = v + Of[off];
        else                    Oh[off] = (f16)v;
      }
    }
  }
}

// ---------------------------------------------------------------------------
// LSTM scan. 64 WGs x 512 threads. Thread t: unit u=t>>1, pair p=t&1, gate
// columns c0=u*4+2p, c0+1 (p=0 -> f,i ; p=1 -> g,o). 2 waves/SIMD.
// Weights per thread 256 u32: wv[96] VGPR (k=0..191) + 16 uint4 in LDS
// (k=192..255, manual spill, b128 lane-contig reads). hx in LDS double
// buffer (broadcast reads). Gate exchange within lane-pairs via shfl_xor.
// Wscan NOT __restrict__ (blocks remat of wv into loop).
// ---------------------------------------------------------------------------
__global__ __launch_bounds__(512, 2)
void scan_k(const f16* __restrict__ Xp, const f16* Wscan,
            float* __restrict__ dout, f16* __restrict__ Hh)
{
  extern __shared__ char smem[];
  uint4* wtl = (uint4*)smem;                    // [16 j][512 t]  (128 KB)
  f16* hxbuf = (f16*)(smem + 131072);           // [2][256]
  const int tid = threadIdx.x;
  const int b = blockIdx.x;
  const int u = tid >> 1;
  const int p = tid & 1;
  const int c0 = u * 4 + p * 2;
  const unsigned* W32 = (const unsigned*)Wscan; // [128 r][1024 c]

  uint2 wv[96];                                 // k-pairs 0..95, cols c0,c0+1
  #pragma unroll
  for (int r = 0; r < 96; ++r)
    wv[r] = *(const uint2*)(W32 + r * 1024 + c0);

  #pragma unroll
  for (int j = 0; j < 16; ++j) {                // k-pairs 96..127 -> LDS
    uint2 e0 = *(const uint2*)(W32 + (96 + 2 * j) * 1024 + c0);
    uint2 e1 = *(const uint2*)(W32 + (97 + 2 * j) * 1024 + c0);
    uint4 w; w.x = e0.x; w.y = e0.y; w.z = e1.x; w.w = e1.y;
    wtl[j * 512 + tid] = w;
  }
  if (tid < 256) hxbuf[tid] = (f16)0.f;         // buffer 0 zeros for t=0
  float cx = 0.f, hv = 0.f;
  const unsigned* Xp32 = (const unsigned*)Xp;
  __syncthreads();

  #pragma unroll 1
  for (int t = 0; t < 1024; ++t) {
    unsigned xp = Xp32[(size_t)(t * 64 + b) * 512 + tid];  // gates 2p,2p+1
    const f16* hx = hxbuf + (t & 1) * 256;
    float a0 = 0.f, a1 = 0.f;
    #pragma unroll
    for (int q = 0; q < 24; ++q) {              // k = 0..191 (VGPR weights)
      half8v h8 = *(const half8v*)(hx + q * 8);
      const half2v* hp = (const half2v*)&h8;
      #pragma unroll
      for (int z = 0; z < 4; ++z) {
        uint2 w = wv[q * 4 + z];
        a0 = __builtin_amdgcn_fdot2(hp[z], u2h(w.x), a0, false);
        a1 = __builtin_amdgcn_fdot2(hp[z], u2h(w.y), a1, false);
      }
    }
    #pragma unroll
    for (int j = 0; j < 8; ++j) {               // k = 192..255 (LDS weights)
      half8v h8 = *(const half8v*)(hx + 192 + j * 8);
      const half2v* hp = (const half2v*)&h8;
      uint4 wA = wtl[(2 * j) * 512 + tid];      // k-pairs 96+4j, 97+4j
      uint4 wB = wtl[(2 * j + 1) * 512 + tid];  // k-pairs 98+4j, 99+4j
      a0 = __builtin_amdgcn_fdot2(hp[0], u2h(wA.x), a0, false);
      a1 = __builtin_amdgcn_fdot2(hp[0], u2h(wA.y), a1, false);
      a0 = __builtin_amdgcn_fdot2(hp[1], u2h(wA.z), a0, false);
      a1 = __builtin_amdgcn_fdot2(hp[1], u2h(wA.w), a1, false);
      a0 = __builtin_amdgcn_fdot2(hp[2], u2h(wB.x), a0, false);
      a1 = __builtin_amdgcn_fdot2(hp[2], u2h(wB.y), a1, false);
      a0 = __builtin_amdgcn_fdot2(hp[3], u2h(wB.z), a0, false);
      a1 = __builtin_amdgcn_fdot2(hp[3], u2h(wB.w), a1, false);
    }
    half2v xh = u2h(xp);
    float e0 = a0 + (float)xh.x;
    float e1 = a1 + (float)xh.y;
    float v0 = p ? tanh_fast(e0) : sigm(e0);    // p=0: f ; p=1: g
    float v1 = sigm(e1);                        // p=0: i ; p=1: o
    float ov0 = __shfl_xor(v0, 1);
    float ov1 = __shfl_xor(v1, 1);
    if (p == 0) {
      cx = v0 * cx + v1 * ov0;                  // f*cx + i*g
      hv = ov1 * tanh_fast(cx);                 // o*tanh(cx)
      hxbuf[((t + 1) & 1) * 256 + u] = (f16)hv;
      size_t off = (size_t)(t * 64 + b) * 256 + u;
      dout[off] = hv;
      Hh[off] = (f16)hv;
    }
    __syncthreads();
  }
  if (p == 0) {
    dout[(size_t)16777216 + b * 256 + u] = hv;            // hx
    dout[(size_t)16777216 + 16384 + b * 256 + u] = cx;    // cx
  }
}

// ---------------------------------------------------------------------------
// Fused batch-axis attention, one WG per (s, head). (unchanged)
// ---------------------------------------------------------------------------
__global__ __launch_bounds__(256, 2) void attn_k(const f16* __restrict__ qkv,
                                                 f16* __restrict__ ctx)
{
  __shared__ f16 ql[64 * 72];
  __shared__ f16 kl[64 * 72];
  __shared__ f16 vT[64 * 72];     // transposed: [d][k_b]
  __shared__ f16 at[64 * 72];     // exp'd scores (unnormalized), [q_b][k_b]
  __shared__ float sc[64 * 69];
  __shared__ float pmx[256], psm[256], rmx[64], rsm[64];
  const int tid = threadIdx.x;
  const int s = blockIdx.x >> 2, h = blockIdx.x & 3;
  {
    const int bb = tid >> 2, i = tid & 3;
    const f16* base = qkv + (size_t)(s * 64 + bb) * 768 + h * 64 + i * 16;
    half8v q0 = *(const half8v*)(base);
    half8v q1 = *(const half8v*)(base + 8);
    *(half8v*)(ql + bb * 72 + i * 16)     = q0;
    *(half8v*)(ql + bb * 72 + i * 16 + 8) = q1;
    half8v k0 = *(const half8v*)(base + 256);
    half8v k1 = *(const half8v*)(base + 264);
    *(half8v*)(kl + bb * 72 + i * 16)     = k0;
    *(half8v*)(kl + bb * 72 + i * 16 + 8) = k1;
    half8v v0 = *(const half8v*)(base + 512);
    half8v v1 = *(const half8v*)(base + 520);
    #pragma unroll
    for (int z = 0; z < 8; ++z) {
      vT[(i * 16 + z) * 72 + bb]     = v0[z];
      vT[(i * 16 + 8 + z) * 72 + bb] = v1[z];
    }
  }
  __syncthreads();
  {
    const int qb = tid >> 2, g = tid & 3;
    half8v qr[8];
    #pragma unroll
    for (int i = 0; i < 8; ++i) qr[i] = *(const half8v*)(ql + qb * 72 + i * 8);
    #pragma unroll 1
    for (int jj = 0; jj < 16; ++jj) {
      int kb = g + jj * 4;
      float a = 0.0f;
      #pragma unroll
      for (int i = 0; i < 8; ++i) {
        half8v kr = *(const half8v*)(kl + kb * 72 + i * 8);
        const half2v* kp = (const half2v*)&kr;
        const half2v* qp = (const half2v*)&qr[i];
        #pragma unroll
        for (int z = 0; z < 4; ++z) a = __builtin_amdgcn_fdot2(qp[z], kp[z], a, false);
      }
      sc[qb * 69 + kb] = a * 0.125f;
    }
  }
  __syncthreads();
  {
    const int r = tid & 63, q = tid >> 6;
    float m = -1e30f;
    #pragma unroll
    for (int z = 0; z < 16; ++z) m = fmaxf(m, sc[r * 69 + q * 16 + z]);
    pmx[q * 64 + r] = m;
  }
  __syncthreads();
  if (tid < 64)
    rmx[tid] = fmaxf(fmaxf(pmx[tid], pmx[64 + tid]), fmaxf(pmx[128 + tid], pmx[192 + tid]));
  __syncthreads();
  {
    const int r = tid & 63, q = tid >> 6;
    float mx = rmx[r], ssum = 0.0f;
    #pragma unroll
    for (int z = 0; z < 16; ++z) {
      float e = __expf(sc[r * 69 + q * 16 + z] - mx);
      ssum += e;
      at[r * 72 + q * 16 + z] = (f16)e;
    }
    psm[q * 64 + r] = ssum;
  }
  __syncthreads();
  if (tid < 64)
    rsm[tid] = (psm[tid] + psm[64 + tid]) + (psm[128 + tid] + psm[192 + tid]);
  __syncthreads();
  {
    const int qb = tid >> 2, g = tid & 3;
    half8v ar[8];
    #pragma unroll
    for (int i = 0; i < 8; ++i) ar[i] = *(const half8v*)(at + qb * 72 + i * 8);
    const float rinv = 1.0f / rsm[qb];
    f16* outp = ctx + (size_t)(s * 64 + qb) * 256 + h * 64;
    #pragma unroll 1
    for (int z = 0; z < 16; ++z) {
      int d = g + z * 4;
      float a = 0.0f;
      #pragma unroll
      for (int i = 0; i < 8; ++i) {
        half8v vr = *(const half8v*)(vT + d * 72 + i * 8);
        const half2v* vp = (const half2v*)&vr;
        const half2v* ap = (const half2v*)&ar[i];
        #pragma unroll
        for (int zz = 0; zz < 4; ++zz) a = __builtin_amdgcn_fdot2(ap[zz], vp[zz], a, false);
      }
      outp[d] = (f16)(a * rinv);
    }
  }
}

// ---------------------------------------------------------------------------
extern "C" void kernel_launch(void* const* d_in, const int* in_sizes, int n_in,
                              void* d_out, int out_size, void* d_ws, size_t ws_size,
                              hipStream_t stream)
{
  (void)in_sizes; (void)n_in; (void)out_size; (void)ws_size;
  const float* X    = (const float*)d_in[0];
  const float* Wf   = (const float*)d_in[1];
  const float* bf   = (const float*)d_in[2];
  const float* Wi   = (const float*)d_in[3];
  const float* bi   = (const float*)d_in[4];
  const float* Wg   = (const float*)d_in[5];
  const float* bg   = (const float*)d_in[6];
  const float* Wo   = (const float*)d_in[7];
  const float* bo   = (const float*)d_in[8];
  const float* inpw = (const float*)d_in[9];
  const float* inpb = (const float*)d_in[10];
  const float* outpw= (const float*)d_in[11];
  const float* outpb= (const float*)d_in[12];

  char* ws = (char*)d_ws;
  f16*   Xp    = (f16*)(ws + 0);
  f16*   qkv   = (f16*)(ws + 0);                 // reuses Xp region after scan
  f16*   ctxh  = (f16*)(ws + 100663296);         // also inside old Xp region
  f16*   Xh    = (f16*)(ws + 134217728);
  f16*   Hh    = (f16*)(ws + 167772160);
  f16*   wscan = (f16*)(ws + 201326592);
  f16*   wxt   = (f16*)(ws + 201850880);
  f16*   inpj  = (f16*)(ws + 202375168);
  f16*   outpj = (f16*)(ws + 202768384);
  float* bias4 = (float*)(ws + 202899456);
  float* out   = (float*)d_out;

  prep_k<<<1024, 256, 0, stream>>>(Wf, Wi, Wg, Wo, bf, bi, bg, bo, inpw, outpw,
                                   wscan, wxt, inpj, outpj, bias4);
  cvt_x_k<<<16384, 256, 0, stream>>>((const float4v*)X, (half4v*)Xh);
  gemm_k<1024, 1><<<dim3(8, 512), 256, 0, stream>>>(Xh, wxt, bias4, Xp, nullptr);
  scan_k<<<64, 512, 132096, stream>>>(Xp, wscan, out, Hh);
  gemm_k<768, 0><<<dim3(6, 512), 256, 0, stream>>>(Hh, inpj, inpb, qkv, nullptr);
  attn_k<<<4096, 256, 0, stream>>>(qkv, ctxh);
  gemm_k<256, 2><<<dim3(2, 512), 256, 0, stream>>>(ctxh, outpj, outpb, nullptr, out);
}